// Round 11
// baseline (376.109 us; speedup 1.0000x reference)
//
#include <hip/hip_runtime.h>
#include <math.h>

// ViT Vector Quantizer: z [32,1024,32] f32, embedding [8192,32] f32.
// Outputs (concat, read as f32): z_q_out [N*D], loss [1], idx [N] (as floats).
//
// R11: TWO dispatches.
//   K0 k_prep : codebook normalize -> en, en_h, bf16 hi/lo B-frag swizzle (eswz);
//               zero loss + tick.
//   K1 k_main : grid (N/256, KSPLIT=16), 256 thr, 2x16KB LDS double buffer
//               (33 KB -> 4 blocks/CU, 16 waves/CU: barrier drains overlap
//               across blocks -- R8's 2 blocks/CU exposed 28us of stalls).
//               Block (rb,s): stage 512 codes in 4 chunks; 4 row-groups/wave
//               (64 rows); per tile 3-MFMA split-bf16 chain + packed-u32 top-2
//               (5-bit tile idx). Per-split result packed (s1q:28|s2q:27|~k:9)
//               into ONE u64 -> ws stays 6.06 MB (< 6.7 MB proven).
//               Ticket: 16th block per rb merges splits, flags gap < 6e-5,
//               exact-rescores flagged rows in-block, gathers en[idx],
//               writes z_q_out / idx / loss. No separate epi dispatch.

#define D 32
#define KCODES 8192
#define KSPLIT 16
#define CODES_PB 512        // codes per block (split)
#define NCHUNK 4            // 4 chunks x 128 codes (8 tiles, 16 KB)
#define MASK5 0xFFFFFFE0u   // keep 27 high bits; low 5 = (31 - tile)
#define MARGIN 6.0e-5f      // > 2*(split-bf16 ~1.5e-5) + quant (~8e-6) + slack
#define EPS 1e-12f

typedef short bf16x8 __attribute__((ext_vector_type(8)));
typedef unsigned short u16x8 __attribute__((ext_vector_type(8)));
typedef float f32x4 __attribute__((ext_vector_type(4)));
typedef unsigned long long u64;

static __device__ __forceinline__ unsigned short f2bf(float x) {  // RNE bf16 bits
  unsigned u = __float_as_uint(x);
  return (unsigned short)((u + 0x7FFFu + ((u >> 16) & 1u)) >> 16);
}
static __device__ __forceinline__ float bf2f(unsigned short s) {
  return __uint_as_float(((unsigned)s) << 16);
}
static __device__ __forceinline__ void gload_lds16(const void* g, void* l) {
  __builtin_amdgcn_global_load_lds(
      (const __attribute__((address_space(1))) void*)g,
      (__attribute__((address_space(3))) void*)l, 16, 0, 0);
}

// MFMA fragment layouts (validated by R5-R10 exact-idx passes):
//   A[m][k]: m = lane&15, k = (lane>>4)*8 + j
//   B[k][n]: n = lane&15, k = (lane>>4)*8 + j
//   C[m][n]: n = lane&15, m = (lane>>4)*4 + reg

__global__ __launch_bounds__(256) void k_prep(const float* __restrict__ emb,
                                              float* __restrict__ en,
                                              float* __restrict__ en_h,
                                              unsigned short* __restrict__ eswz,
                                              float* __restrict__ loss,
                                              int* __restrict__ tick,
                                              int ntick) {
  int v = blockIdx.x * 256 + threadIdx.x;
  if (v == 0) *loss = 0.f;
  if (v < ntick) tick[v] = 0;
  if (v >= KCODES) return;

  float x[D];
  const float4* p = reinterpret_cast<const float4*>(emb + (size_t)v * D);
#pragma unroll
  for (int j = 0; j < D / 4; ++j) {
    float4 q = p[j];
    x[4 * j + 0] = q.x; x[4 * j + 1] = q.y; x[4 * j + 2] = q.z; x[4 * j + 3] = q.w;
  }
  float ss = 0.f;
#pragma unroll
  for (int j = 0; j < D; ++j) ss = fmaf(x[j], x[j], ss);
  float n = fmaxf(sqrtf(ss), EPS);
#pragma unroll
  for (int j = 0; j < D; ++j) x[j] = x[j] / n;   // true division mirrors reference

  float4* o = reinterpret_cast<float4*>(en + (size_t)v * D);
  float s2 = 0.f;
#pragma unroll
  for (int j = 0; j < D / 4; ++j) {
    float4 q = {x[4 * j], x[4 * j + 1], x[4 * j + 2], x[4 * j + 3]};
    s2 = fmaf(q.x, q.x, fmaf(q.y, q.y, fmaf(q.z, q.z, fmaf(q.w, q.w, s2))));
    o[j] = q;
  }
  en_h[v] = 0.5f * s2;

  unsigned short hi[D], lo[D];
#pragma unroll
  for (int j = 0; j < D; ++j) {
    hi[j] = f2bf(x[j]);
    lo[j] = f2bf(x[j] - bf2f(hi[j]));   // x - bf16(x) exact in fp32
  }
  int tl = v >> 4, m = v & 15;          // B-frag swizzle: global tile = 1024 shorts
#pragma unroll
  for (int q = 0; q < 4; ++q) {
    u16x8 hv, lv;
#pragma unroll
    for (int j = 0; j < 8; ++j) { hv[j] = hi[8 * q + j]; lv[j] = lo[8 * q + j]; }
    *(u16x8*)(eswz + (size_t)tl * 1024 + (q * 16 + m) * 8) = hv;
    *(u16x8*)(eswz + (size_t)tl * 1024 + 512 + (q * 16 + m) * 8) = lv;
  }
}

__global__ __launch_bounds__(256, 4) void k_main(
    const float* __restrict__ z,
    const unsigned short* __restrict__ eswz,
    const float* __restrict__ en,
    const float* __restrict__ en_h,
    u64* __restrict__ mpp,              // [KSPLIT][N] packed per-split results
    int* __restrict__ tick,
    float* __restrict__ out_z, float* __restrict__ loss,
    float* __restrict__ out_idx, float scale, int N) {
  __shared__ unsigned short sbuf[2][8192];   // 2 x 16 KB double buffer
  __shared__ int s_old;
  __shared__ int nflag;
  __shared__ int flist[256];
  __shared__ int fres[256];
  __shared__ u64 wred[4];
  __shared__ float wsum[4];

  const int tid = threadIdx.x;
  const int wid = tid >> 6, lane = tid & 63;
  const int lane15 = lane & 15, quad = lane >> 4;
  const int rb = blockIdx.x;                 // row-block (256 rows)
  const int split = blockIdx.y;              // 512-code split
  const int rowbase = rb * 256 + wid * 64;   // this wave's 64 rows

  // stage chunk 0 (global tiles split*32 .. +7) -- overlaps the z prologue
  {
    const float4* gsrc =
        reinterpret_cast<const float4*>(eswz) + (size_t)(split * 32) * 128;
#pragma unroll
    for (int i = 0; i < 4; ++i) {
      int off = i * 256 + tid;               // wave-uniform base + lane*16B
      gload_lds16(gsrc + off, (char*)&sbuf[0][0] + (size_t)off * 16);
    }
  }

  // --- A-fragments for 4 row groups (validated R10 prologue) ---
  bf16x8 zh[4], zl[4];
#pragma unroll
  for (int g = 0; g < 4; ++g) {
    const float4* p =
        reinterpret_cast<const float4*>(z + (size_t)(rowbase + g * 16 + lane15) * D);
    float ss = 0.f;
#pragma unroll
    for (int j = 0; j < 8; ++j) {
      float4 q = p[j];
      ss = fmaf(q.x, q.x, fmaf(q.y, q.y, fmaf(q.z, q.z, fmaf(q.w, q.w, ss))));
    }
    float nn = fmaxf(sqrtf(ss), EPS);
    float4 a0 = p[quad * 2], a1 = p[quad * 2 + 1];
    float xs[8] = {a0.x / nn, a0.y / nn, a0.z / nn, a0.w / nn,
                   a1.x / nn, a1.y / nn, a1.z / nn, a1.w / nn};
#pragma unroll
    for (int j = 0; j < 8; ++j) {
      unsigned short h = f2bf(xs[j]);
      zh[g][j] = (short)h;
      zl[g][j] = (short)f2bf(xs[j] - bf2f(h));
    }
  }

  unsigned p1[4][4], p2[4][4];
#pragma unroll
  for (int g = 0; g < 4; ++g)
#pragma unroll
    for (int r = 0; r < 4; ++r) { p1[g][r] = 0u; p2[g][r] = 0u; }
  const f32x4 initc = {1.25f, 1.25f, 1.25f, 1.25f};  // s' = 1.25 + dot > 0

  for (int c = 0; c < NCHUNK; ++c) {
    __syncthreads();                 // buffer c&1 fully staged (vmcnt drained)
    if (c + 1 < NCHUNK) {            // next chunk's DMA overlaps this compute
      const float4* gn = reinterpret_cast<const float4*>(eswz) +
                         (size_t)(split * 32 + (c + 1) * 8) * 128;
      char* dst = (char*)&sbuf[(c + 1) & 1][0];
#pragma unroll
      for (int i = 0; i < 4; ++i) {
        int off = i * 256 + tid;
        gload_lds16(gn + off, dst + (size_t)off * 16);
      }
    }
    const unsigned short* buf = &sbuf[c & 1][0];
#pragma unroll
    for (int t = 0; t < 8; ++t) {
      bf16x8 bh = *(const bf16x8*)(buf + t * 1024 + lane * 8);
      bf16x8 bl = *(const bf16x8*)(buf + t * 1024 + 512 + lane * 8);
      const unsigned tid5 = (unsigned)(31 - (c * 8 + t));
#pragma unroll
      for (int g = 0; g < 4; ++g) {         // 4 independent 3-MFMA chains
        f32x4 acc = __builtin_amdgcn_mfma_f32_16x16x32_bf16(zh[g], bh, initc, 0, 0, 0);
        acc = __builtin_amdgcn_mfma_f32_16x16x32_bf16(zh[g], bl, acc, 0, 0, 0);
        acc = __builtin_amdgcn_mfma_f32_16x16x32_bf16(zl[g], bh, acc, 0, 0, 0);
#pragma unroll
        for (int r = 0; r < 4; ++r) {
          unsigned q = (__float_as_uint(acc[r]) & MASK5) | tid5;
          unsigned tm = min(q, p1[g][r]);
          p1[g][r] = max(q, p1[g][r]);
          p2[g][r] = max(tm, p2[g][r]);
        }
      }
    }
  }

  // --- cross-lane merge (16 lanes of each quad hold different codes), pack, store
#pragma unroll
  for (int g = 0; g < 4; ++g) {
#pragma unroll
    for (int r = 0; r < 4; ++r) {
      unsigned pv = p1[g][r];
      unsigned sb = pv & MASK5;
      int tile = 31 - (int)(pv & 31u);
      int klocal = tile * 16 + lane15;           // code within split [0,512)
      float s1f = __uint_as_float(sb);
      float s2f = __uint_as_float(p2[g][r] & MASK5);
      u64 pk = ((u64)sb << 32) | (unsigned)(511 - klocal);
#pragma unroll
      for (int m = 1; m <= 8; m <<= 1) {
        u64 op = __shfl_xor(pk, m, 64);
        float os1 = __shfl_xor(s1f, m, 64);
        float os2 = __shfl_xor(s2f, m, 64);
        s2f = fmaxf(fmaxf(s2f, os2), fminf(s1f, os1));  // union 2nd-best
        s1f = fmaxf(s1f, os1);
        pk = (op > pk) ? op : pk;                       // max s, tie -> min k
      }
      if (lane15 == 0) {
        int row = rowbase + g * 16 + quad * 4 + r;
        unsigned sbw = (unsigned)(pk >> 32);
        unsigned s2w = __float_as_uint(s2f);
        // pack [s1q:28 | s2q:27 | (511-klocal):9]
        mpp[(size_t)split * N + row] = ((u64)(sbw >> 4) << 36) |
                                       ((u64)(s2w >> 5) << 9) |
                                       (pk & 511u);
      }
    }
  }

  // --- ticket: last split block for this row-block merges + does the epilogue
  __threadfence();
  __syncthreads();
  if (tid == 0) s_old = atomicAdd(&tick[rb], 1);
  __syncthreads();
  if (s_old != KSPLIT - 1) return;
  __threadfence();

  int row = rb * 256 + tid;                 // one row per thread
  u64 kk[KSPLIT];
  u64 B = 0ull;
#pragma unroll
  for (int s = 0; s < KSPLIT; ++s) {
    kk[s] = mpp[(size_t)s * N + row];
    B = (kk[s] > B) ? kk[s] : B;
  }
  int swin = 0;
#pragma unroll
  for (int s = KSPLIT - 1; s >= 0; --s) if (kk[s] == B) swin = s;  // first match
  float s1g = __uint_as_float((unsigned)(B >> 36) << 4);
  float s2g = __uint_as_float(((unsigned)(B >> 9) & 0x7FFFFFFu) << 5);
#pragma unroll
  for (int s = 0; s < KSPLIT; ++s)
    if (s != swin)
      s2g = fmaxf(s2g, __uint_as_float((unsigned)(kk[s] >> 36) << 4));
  int kb = swin * CODES_PB + (511 - (int)(B & 511u));

  if (tid == 0) nflag = 0;
  __syncthreads();
  int myslot = -1;
  if (s1g - s2g < MARGIN) { myslot = atomicAdd(&nflag, 1); flist[myslot] = row; }
  __syncthreads();
  const int nf = nflag;

  for (int f = 0; f < nf; ++f) {            // exact fp32 rescore, thread-per-code
    int frow = flist[f];
    const float* zr = z + (size_t)frow * D; // uniform -> scalar loads
    float v[D];
    float ss = 0.f;
#pragma unroll
    for (int d = 0; d < D; ++d) v[d] = zr[d];
#pragma unroll
    for (int d = 0; d < D; ++d) ss = fmaf(v[d], v[d], ss);
    float nn = fmaxf(sqrtf(ss), EPS);
#pragma unroll
    for (int d = 0; d < D; ++d) v[d] = v[d] / nn;

    u64 best = 0ull;
    for (int k = tid; k < KCODES; k += 256) {   // coalesced across threads
      const float4* er = reinterpret_cast<const float4*>(en + (size_t)k * D);
      float a = -en_h[k];
#pragma unroll
      for (int jj = 0; jj < 8; ++jj) {
        float4 e = er[jj];
        a = fmaf(v[4 * jj + 0], e.x, a);
        a = fmaf(v[4 * jj + 1], e.y, a);
        a = fmaf(v[4 * jj + 2], e.z, a);
        a = fmaf(v[4 * jj + 3], e.w, a);
      }
      unsigned o = __float_as_uint(a);
      o = (o & 0x80000000u) ? ~o : (o | 0x80000000u);
      u64 pk = ((u64)o << 32) | (unsigned)(8191 - k);
      best = (pk > best) ? pk : best;           // max s, tie -> min k
    }
#pragma unroll
    for (int m = 32; m >= 1; m >>= 1) {
      u64 op = __shfl_xor(best, m, 64);
      best = (op > best) ? op : best;
    }
    if (lane == 0) wred[wid] = best;
    __syncthreads();
    if (tid == 0) {
      u64 m01 = (wred[0] > wred[1]) ? wred[0] : wred[1];
      u64 m23 = (wred[2] > wred[3]) ? wred[2] : wred[3];
      u64 M = (m01 > m23) ? m01 : m23;
      fres[f] = 8191 - (int)(unsigned)(M & 0xFFFFFFFFull);
    }
    __syncthreads();
  }
  if (myslot >= 0) kb = fres[myslot];

  // --- epilogue: gather en[kb], STE output, idx, loss ---
  out_idx[row] = (float)kb;

  const float4* p = reinterpret_cast<const float4*>(z + (size_t)row * D);
  float4 q[D / 4];
#pragma unroll
  for (int j = 0; j < D / 4; ++j) q[j] = p[j];
  float ss2 = 0.f;
#pragma unroll
  for (int j = 0; j < D / 4; ++j)
    ss2 = fmaf(q[j].x, q[j].x, fmaf(q[j].y, q[j].y, fmaf(q[j].z, q[j].z, fmaf(q[j].w, q[j].w, ss2))));
  float n2 = fmaxf(sqrtf(ss2), EPS);

  const float4* ep = reinterpret_cast<const float4*>(en + (size_t)kb * D);
  float4* op = reinterpret_cast<float4*>(out_z + (size_t)row * D);
  float s = 0.f;
#pragma unroll
  for (int j = 0; j < D / 4; ++j) {
    float4 e = ep[j];
    float4 o;
    o.x = q[j].x + (e.x - q[j].x);  // STE forward value, reference op order
    o.y = q[j].y + (e.y - q[j].y);
    o.z = q[j].z + (e.z - q[j].z);
    o.w = q[j].w + (e.w - q[j].w);
    op[j] = o;
    float dx = e.x - q[j].x / n2;  float dy = e.y - q[j].y / n2;
    float dz = e.z - q[j].z / n2;  float dw = e.w - q[j].w / n2;
    s = fmaf(dx, dx, fmaf(dy, dy, fmaf(dz, dz, fmaf(dw, dw, s))));
  }

#pragma unroll
  for (int off = 32; off > 0; off >>= 1) s += __shfl_down(s, off, 64);
  if (lane == 0) wsum[wid] = s;
  __syncthreads();
  if (tid == 0) {
    float tt = (wsum[0] + wsum[1]) + (wsum[2] + wsum[3]);
    atomicAdd(loss, tt * scale);
  }
}

extern "C" void kernel_launch(void* const* d_in, const int* in_sizes, int n_in,
                              void* d_out, int out_size, void* d_ws, size_t ws_size,
                              hipStream_t stream) {
  const float* z = (const float*)d_in[0];
  const float* emb = (const float*)d_in[1];
  const int N = in_sizes[0] / D;  // 32768
  const int K = in_sizes[1] / D;  // 8192

  float* out = (float*)d_out;
  float* out_z = out;                        // N*D
  float* loss = out + (size_t)N * D;         // 1
  float* out_idx = out + (size_t)N * D + 1;  // N

  // ws layout (6.06 MB total; harness ws >= 6.7 MB proven by R7-R10)
  char* w = (char*)d_ws;
  u64* mpp = (u64*)w;                            w += (size_t)KSPLIT * N * 8;  // 4 MB
  float* en = (float*)w;                         w += (size_t)K * D * 4;       // 1 MB
  float* en_h = (float*)w;                       w += (size_t)K * 4;           // 32 KB
  unsigned short* eswz = (unsigned short*)w;     w += (size_t)K * D * 2 * 2;   // 1 MB
  int* tick = (int*)w;                           w += 1024;

  const int nrb = N / 256;   // 128 row-blocks

  k_prep<<<dim3(K / 256), 256, 0, stream>>>(emb, en, en_h, eswz, loss, tick, nrb);

  k_main<<<dim3(nrb, KSPLIT), 256, 0, stream>>>(
      z, eswz, en, en_h, mpp, tick, out_z, loss, out_idx,
      1.25f / (float)((size_t)N * D), N);
}